// Round 2
// 833.796 us; speedup vs baseline: 1.0986x; 1.0986x over previous
//
#include <hip/hip_runtime.h>
#include <cstdint>
#include <cstddef>

// Problem dims
#define BDIM 8192
#define D1 1024
#define HDIM 4096

typedef __attribute__((ext_vector_type(8))) short short8;
typedef __attribute__((ext_vector_type(4))) float f32x4;
typedef __attribute__((ext_vector_type(4))) unsigned short u16x4;

__device__ inline void async_load16(const void* g, void* l) {
  __builtin_amdgcn_global_load_lds(
      (const __attribute__((address_space(1))) void*)g,
      (__attribute__((address_space(3))) void*)l,
      16 /*bytes*/, 0 /*offset*/, 0 /*aux*/);
}

__device__ inline unsigned short f2bf(float f) {
  union { float f; uint32_t u; } v; v.f = f;
  uint32_t u = v.u;
  uint32_t r = u + 0x7FFFu + ((u >> 16) & 1u);  // RNE
  return (unsigned short)(r >> 16);
}
__device__ inline float bf2f(unsigned short u) {
  union { uint32_t u; float f; } v; v.u = (uint32_t)u << 16; return v.f;
}

// ---------------------------------------------------------------------------
// 256x256 8-wave 8-phase GEMM: C = act(A @ B^T + bias), bf16 in/out.
// A[M,K] row-major (stride lda), B[N,K] row-major (stride K), C[M,*] stride ldc.
// gridDim.z = 2 selects the (A,B,bias,C) tuple -> two GEMMs in one launch.
// Schedule: per K-tile (BK=64) 4 phases = (m-half x k-slice); each phase:
//   {ds_read subtile | stage 1 half-tile (2x global_load_lds dwordx4)}
//   s_barrier ; [compiler lgkmcnt] ; setprio(1) ; 16x MFMA ; setprio(0) ; s_barrier
// vmcnt(4) (never 0) before the trailing barrier of phases 2 and 4 of each
// tile: the 4 loads left in flight are exactly the not-yet-needed half-tiles.
// LDS: [2buf][2slice][256 rows][32 cols] bf16 per matrix = 64KB+64KB = 128KB.
// Swizzle: 16B slot p holds logical k-group p ^ ((row>>1)&3) (involution),
// applied on the pre-swizzled global source (stage) and on ds_read -> 2-way.
// ---------------------------------------------------------------------------
__global__ __launch_bounds__(512, 2)
void gemm8(const unsigned short* __restrict__ A0,
           const unsigned short* __restrict__ A1, int lda,
           const unsigned short* __restrict__ B0,
           const unsigned short* __restrict__ B1,
           const float* __restrict__ bias0, const float* __restrict__ bias1,
           unsigned short* __restrict__ C0, unsigned short* __restrict__ C1,
           int ldc, int K, int relu) {
  __shared__ __align__(16) unsigned short smem[65536];  // A:[0,32768) B:[32768,65536)

  const int z = blockIdx.z;
  const unsigned short* A  = z ? A1 : A0;
  const unsigned short* Bw = z ? B1 : B0;
  const float* biasP       = z ? bias1 : bias0;
  unsigned short* C        = z ? C1 : C0;

  // bijective XCD swizzle (m204)
  const int nX  = gridDim.x;
  const int nwg = gridDim.x * gridDim.y;
  const int bid = blockIdx.y * gridDim.x + blockIdx.x;
  const int q = nwg >> 3, r = nwg & 7;
  const int xcd = bid & 7, rest = bid >> 3;
  const int wg = (xcd < r ? xcd * (q + 1) : r * (q + 1) + (xcd - r) * q) + rest;
  const int tm = wg / nX, tn = wg % nX;
  const int m0 = tm * 256, n0 = tn * 256;

  const int tid  = threadIdx.x;
  const int wave = tid >> 6, lane = tid & 63;
  const int quad = lane >> 4, l15 = lane & 15;
  const int wm = wave >> 2, wn = wave & 3;   // 2 x 4 wave grid; wave tile 128x64

  // staging source (pre-swizzled global address; LDS dest stays linear)
  const int sr    = tid >> 2;                         // 0..127
  const int sslot = (tid & 3) ^ ((tid >> 3) & 3);     // involutive 16B-slot swizzle
  const unsigned short* gA = A  + (long)(m0 + sr) * lda + sslot * 8;
  const unsigned short* gB = Bw + (long)(n0 + sr) * K   + sslot * 8;

  // LDS read bases (swizzled)
  const int swz = ((quad ^ ((l15 >> 1) & 3)) << 3);   // ushort units
  const unsigned short* aB = smem + wm * 4096  + l15 * 32 + swz;
  const unsigned short* bB = smem + 32768 + wn * 2048 + l15 * 32 + swz;

  f32x4 acc[8][4] = {};
  const int NT = K >> 6;

#define STAGE_A(NB, SL, KT) { \
  unsigned short* lw = smem + (NB)*16384 + (SL)*8192 + wave*512; \
  const unsigned short* g = gA + (long)(KT)*64 + (SL)*32; \
  async_load16(g, lw); \
  async_load16(g + 128*(long)lda, lw + 4096); }

#define STAGE_B(NB, SL, KT) { \
  unsigned short* lw = smem + 32768 + (NB)*16384 + (SL)*8192 + wave*512; \
  const unsigned short* g = gB + (long)(KT)*64 + (SL)*32; \
  async_load16(g, lw); \
  async_load16(g + 128*(long)K, lw + 4096); }

#define READ_A(dst, BUF, SL, MH) { \
  const unsigned short* p = aB + (BUF)*16384 + (SL)*8192 + (MH)*2048; \
  dst[0] = *(const short8*)(p);        dst[1] = *(const short8*)(p + 512); \
  dst[2] = *(const short8*)(p + 1024); dst[3] = *(const short8*)(p + 1536); }

#define READ_B(dst, BUF, SL) { \
  const unsigned short* p = bB + (BUF)*16384 + (SL)*8192; \
  dst[0] = *(const short8*)(p);        dst[1] = *(const short8*)(p + 512); \
  dst[2] = *(const short8*)(p + 1024); dst[3] = *(const short8*)(p + 1536); }

#define MFMA16(MH, AV, BV) \
  _Pragma("unroll") \
  for (int mt = 0; mt < 4; ++mt) { \
    _Pragma("unroll") \
    for (int nt = 0; nt < 4; ++nt) { \
      acc[(MH)*4 + mt][nt] = __builtin_amdgcn_mfma_f32_16x16x32_bf16( \
          AV[mt], BV[nt], acc[(MH)*4 + mt][nt], 0, 0, 0); \
    } }

#define BARRIER() asm volatile("s_barrier" ::: "memory")
#define VMCNT4()  asm volatile("s_waitcnt vmcnt(4)" ::: "memory")

#define TILE_BODY(BUF, NB, TNX) { \
  short8 a0[4], a1[4], b0v[4], b1v[4]; \
  /* phase 1: (mLo, k0) */ \
  READ_A(a0, BUF, 0, 0); READ_B(b0v, BUF, 0); \
  STAGE_A(NB, 0, TNX); \
  BARRIER(); \
  __builtin_amdgcn_s_setprio(1); MFMA16(0, a0, b0v); __builtin_amdgcn_s_setprio(0); \
  BARRIER(); \
  /* phase 2: (mHi, k0) */ \
  READ_A(a1, BUF, 0, 1); \
  STAGE_B(NB, 0, TNX); \
  VMCNT4(); \
  BARRIER(); \
  __builtin_amdgcn_s_setprio(1); MFMA16(1, a1, b0v); __builtin_amdgcn_s_setprio(0); \
  BARRIER(); \
  /* phase 3: (mLo, k1) */ \
  READ_A(a0, BUF, 1, 0); READ_B(b1v, BUF, 1); \
  STAGE_A(NB, 1, TNX); \
  BARRIER(); \
  __builtin_amdgcn_s_setprio(1); MFMA16(0, a0, b1v); __builtin_amdgcn_s_setprio(0); \
  BARRIER(); \
  /* phase 4: (mHi, k1) */ \
  READ_A(a1, BUF, 1, 1); \
  STAGE_B(NB, 1, TNX); \
  VMCNT4(); \
  BARRIER(); \
  __builtin_amdgcn_s_setprio(1); MFMA16(1, a1, b1v); __builtin_amdgcn_s_setprio(0); \
  BARRIER(); \
}

  // prologue: stage tile 0 into buf 0 (order: A-k0, B-k0, A-k1, B-k1)
  STAGE_A(0, 0, 0); STAGE_B(0, 0, 0); STAGE_A(0, 1, 0); STAGE_B(0, 1, 0);
  VMCNT4();        // k0 slices landed; k1 (4 loads) stays in flight
  BARRIER();

#pragma unroll 1
  for (int t = 0; t < NT; t += 2) {
    const int tnx1 = t + 1;                       // always < NT (NT even)
    const int tnx2 = (t + 2 < NT) ? t + 2 : NT - 1;  // clamp: harmless re-stage
    TILE_BODY(0, 1, tnx1);
    TILE_BODY(1, 0, tnx2);
  }

  // ---- epilogue: drain stage loads, then LDS-bounce for coalesced C writes --
  asm volatile("s_waitcnt vmcnt(0)" ::: "memory");
  BARRIER();   // after this no global_load_lds can still write smem

  unsigned short* sc = smem + wave * 8192;  // private 128x64 bf16 scratch/wave
#pragma unroll
  for (int nt = 0; nt < 4; ++nt) {
    const int col = n0 + wn * 64 + nt * 16 + l15;
    const float bv = biasP[col];
#pragma unroll
    for (int mt = 0; mt < 8; ++mt) {
#pragma unroll
      for (int rr = 0; rr < 4; ++rr) {
        const int lrow = mt * 16 + quad * 4 + rr;
        float v = acc[mt][nt][rr] + bv;
        if (relu) v = v > 0.f ? v : 0.f;
        // bank-conflict-free scratch: XOR col bits 4-5 with row's quad
        sc[lrow * 64 + ((nt * 16 + l15) ^ (((lrow >> 2) & 3) << 4))] = f2bf(v);
      }
    }
  }
  // per-wave private region: no barrier needed (wave-ordered DS ops)
  const long rowbase = m0 + wm * 128;
  const int colbase  = n0 + wn * 64;
#pragma unroll
  for (int i = 0; i < 16; ++i) {
    const int L   = i * 1024 + lane * 16;   // byte offset in wave scratch
    const int row = L >> 7;
    const int sp  = (L & 127) >> 4;
    const int cg  = sp ^ ((((row) >> 2) & 3) << 1);   // undo col-bit-4/5 XOR (slot bits 1-2)
    short8 v = *(const short8*)&sc[row * 64 + sp * 8];
    *(short8*)&C[(rowbase + row) * (long)ldc + colbase + cg * 8] = v;
  }

#undef STAGE_A
#undef STAGE_B
#undef READ_A
#undef READ_B
#undef MFMA16
#undef BARRIER
#undef VMCNT4
#undef TILE_BODY
}

// ---------------------------------------------------------------------------
// Coupling epilogue: sv=tanh(s); y = x[:,xoff+c]*exp(sv)+t; optional y->bf16;
// ld[row] = (or +=) rowsum(sv). One block per row, no atomics.
// NOTE: sb and y1b may alias (in-place); no __restrict__ on them.
// ---------------------------------------------------------------------------
__global__ __launch_bounds__(256)
void couple(const unsigned short* sb, const unsigned short* __restrict__ tb,
            const float* __restrict__ x, float* __restrict__ y,
            unsigned short* y1b, float* __restrict__ ld,
            long growoff, int xoff, int addld) {
  __shared__ float wsum[4];
  const int row = blockIdx.x;
  const long grow = growoff + row;
  const int c = threadIdx.x * 4;

  u16x4 sv4 = *(const u16x4*)&sb[(long)row * 1024 + c];
  u16x4 tv4 = *(const u16x4*)&tb[(long)row * 1024 + c];
  f32x4 xv  = *(const f32x4*)&x[grow * 2048 + xoff + c];
  f32x4 yv;
  unsigned short yb[4];
  float rs = 0.f;
#pragma unroll
  for (int j = 0; j < 4; ++j) {
    float s  = bf2f(sv4[j]);
    float t  = bf2f(tv4[j]);
    float sv = tanhf(s);           // SCALE_LIMIT = 1.0
    rs += sv;
    float yy = xv[j] * __expf(sv) + t;
    yv[j] = yy;
    yb[j] = f2bf(yy);
  }
  *(f32x4*)&y[grow * 2048 + xoff + c] = yv;
  if (y1b) {
    u16x4 o; o[0] = yb[0]; o[1] = yb[1]; o[2] = yb[2]; o[3] = yb[3];
    *(u16x4*)&y1b[(long)row * 1024 + c] = o;
  }
#pragma unroll
  for (int o = 32; o > 0; o >>= 1) rs += __shfl_down(rs, o);
  const int wv = threadIdx.x >> 6, ln = threadIdx.x & 63;
  if (ln == 0) wsum[wv] = rs;
  __syncthreads();
  if (threadIdx.x == 0) {
    float tot = wsum[0] + wsum[1] + wsum[2] + wsum[3];
    if (addld) ld[grow] += tot; else ld[grow] = tot;
  }
}

// ---------------------------------------------------------------------------
// Transpose + fp32->bf16 cast: in[R,C] fp32 -> out[C,R] bf16.
// ---------------------------------------------------------------------------
__global__ __launch_bounds__(256)
void transpose_cast(const float* __restrict__ in, unsigned short* __restrict__ out,
                    int R, int C) {
  __shared__ float tile[32][33];
  const int bx = blockIdx.x * 32;
  const int by = blockIdx.y * 32;
  const int tx = threadIdx.x & 31;
  const int ty = threadIdx.x >> 5;
  for (int j = ty; j < 32; j += 8)
    tile[j][tx] = in[(long)(by + j) * C + bx + tx];
  __syncthreads();
  for (int j = ty; j < 32; j += 8)
    out[(long)(bx + j) * R + by + tx] = f2bf(tile[tx][j]);
}

// x (B, 2048) fp32 -> x2 bf16 packed (B, 1024)
__global__ __launch_bounds__(256)
void cast_x2(const float* __restrict__ x, unsigned short* __restrict__ x2b) {
  long i = (long)blockIdx.x * 256 + threadIdx.x;
  long row = i >> 10, col = i & 1023;
  x2b[i] = f2bf(x[row * (2 * D1) + D1 + col]);
}

// ---------------------------------------------------------------------------
extern "C" void kernel_launch(void* const* d_in, const int* in_sizes, int n_in,
                              void* d_out, int out_size, void* d_ws, size_t ws_size,
                              hipStream_t stream) {
  const float* x     = (const float*)d_in[0];
  const float* s1_W1 = (const float*)d_in[1];
  const float* s1_b1 = (const float*)d_in[2];
  const float* s1_W2 = (const float*)d_in[3];
  const float* s1_b2 = (const float*)d_in[4];
  const float* t1_W1 = (const float*)d_in[5];
  const float* t1_b1 = (const float*)d_in[6];
  const float* t1_W2 = (const float*)d_in[7];
  const float* t1_b2 = (const float*)d_in[8];
  const float* s2_W1 = (const float*)d_in[9];
  const float* s2_b1 = (const float*)d_in[10];
  const float* s2_W2 = (const float*)d_in[11];
  const float* s2_b2 = (const float*)d_in[12];
  const float* t2_W1 = (const float*)d_in[13];
  const float* t2_b1 = (const float*)d_in[14];
  const float* t2_W2 = (const float*)d_in[15];
  const float* t2_b2 = (const float*)d_in[16];

  const size_t MB = 1024UL * 1024UL;
  float* y_out  = (float*)d_out;                           // (B, 2048)
  float* ld_out = (float*)d_out + (long)BDIM * (2 * D1);   // (B,)
  char* ws = (char*)d_ws;

  if (ws_size >= 192 * MB) {
    // NC=1 layout (192MB): w1a@0 w1b@8 w2a@16 w2b@24 | x2b/sbuf@32 (16MB)
    //                      tbuf@48 (16MB) | h@64 (128MB)
    unsigned short* w1a = (unsigned short*)(ws + 0 * MB);
    unsigned short* w1b = (unsigned short*)(ws + 8 * MB);
    unsigned short* w2a = (unsigned short*)(ws + 16 * MB);
    unsigned short* w2b = (unsigned short*)(ws + 24 * MB);
    unsigned short* x2b = (unsigned short*)(ws + 32 * MB);  // x2 -> sbuf -> y1b -> sbuf
    unsigned short* tb  = (unsigned short*)(ws + 48 * MB);
    unsigned short* h   = (unsigned short*)(ws + 64 * MB);

    cast_x2<<<(BDIM * D1) / 256, 256, 0, stream>>>(x, x2b);
    transpose_cast<<<dim3(HDIM / 32, D1 / 32), 256, 0, stream>>>(s1_W1, w1a, D1, HDIM);
    transpose_cast<<<dim3(HDIM / 32, D1 / 32), 256, 0, stream>>>(t1_W1, w1b, D1, HDIM);
    transpose_cast<<<dim3(D1 / 32, HDIM / 32), 256, 0, stream>>>(s1_W2, w2a, HDIM, D1);
    transpose_cast<<<dim3(D1 / 32, HDIM / 32), 256, 0, stream>>>(t1_W2, w2b, HDIM, D1);

    // ---- stage 1 ----
    gemm8<<<dim3(16, 32, 2), 512, 0, stream>>>(x2b, x2b, D1, w1a, w1b,
        s1_b1, t1_b1, h, h + 4096, 2 * HDIM, D1, 1);
    // stage-1 W1 dead -> re-transpose stage-2 W1 into same buffers
    transpose_cast<<<dim3(HDIM / 32, D1 / 32), 256, 0, stream>>>(s2_W1, w1a, D1, HDIM);
    transpose_cast<<<dim3(HDIM / 32, D1 / 32), 256, 0, stream>>>(t2_W1, w1b, D1, HDIM);
    gemm8<<<dim3(4, 32, 2), 512, 0, stream>>>(h, h + 4096, 2 * HDIM, w2a, w2b,
        s1_b2, t1_b2, x2b /*sbuf*/, tb, D1, HDIM, 0);
    transpose_cast<<<dim3(D1 / 32, HDIM / 32), 256, 0, stream>>>(s2_W2, w2a, HDIM, D1);
    transpose_cast<<<dim3(D1 / 32, HDIM / 32), 256, 0, stream>>>(t2_W2, w2b, HDIM, D1);
    couple<<<BDIM, 256, 0, stream>>>(x2b, tb, x, y_out, x2b /*y1b in place*/,
                                     ld_out, 0, 0, 0);
    // ---- stage 2 ----
    gemm8<<<dim3(16, 32, 2), 512, 0, stream>>>(x2b, x2b, D1, w1a, w1b,
        s2_b1, t2_b1, h, h + 4096, 2 * HDIM, D1, 1);
    gemm8<<<dim3(4, 32, 2), 512, 0, stream>>>(h, h + 4096, 2 * HDIM, w2a, w2b,
        s2_b2, t2_b2, x2b /*sbuf*/, tb, D1, HDIM, 0);
    couple<<<BDIM, 256, 0, stream>>>(x2b, tb, x, y_out, nullptr, ld_out, 0, D1, 1);
  } else {
    // Chunked fallback: all 8 weight buffers persistent (64MB) + x2b (16MB)
    // + per-chunk tbuf (16/NC) + h (128/NC).
    int NC = 2;
    while (NC < 16) {
      size_t need = 80 * MB + (16 * MB) / NC + (128 * MB) / NC;
      if (need <= ws_size) break;
      NC <<= 1;
    }
    const int Mrows = BDIM / NC;
    unsigned short* w1s1 = (unsigned short*)(ws + 0 * MB);
    unsigned short* w1t1 = (unsigned short*)(ws + 8 * MB);
    unsigned short* w1s2 = (unsigned short*)(ws + 16 * MB);
    unsigned short* w1t2 = (unsigned short*)(ws + 24 * MB);
    unsigned short* w2s1 = (unsigned short*)(ws + 32 * MB);
    unsigned short* w2t1 = (unsigned short*)(ws + 40 * MB);
    unsigned short* w2s2 = (unsigned short*)(ws + 48 * MB);
    unsigned short* w2t2 = (unsigned short*)(ws + 56 * MB);
    unsigned short* x2b  = (unsigned short*)(ws + 64 * MB);
    unsigned short* tb   = (unsigned short*)(ws + 80 * MB);
    unsigned short* h    = (unsigned short*)(ws + 80 * MB + (16 * MB) / NC);

    cast_x2<<<(BDIM * D1) / 256, 256, 0, stream>>>(x, x2b);
    transpose_cast<<<dim3(HDIM / 32, D1 / 32), 256, 0, stream>>>(s1_W1, w1s1, D1, HDIM);
    transpose_cast<<<dim3(HDIM / 32, D1 / 32), 256, 0, stream>>>(t1_W1, w1t1, D1, HDIM);
    transpose_cast<<<dim3(HDIM / 32, D1 / 32), 256, 0, stream>>>(s2_W1, w1s2, D1, HDIM);
    transpose_cast<<<dim3(HDIM / 32, D1 / 32), 256, 0, stream>>>(t2_W1, w1t2, D1, HDIM);
    transpose_cast<<<dim3(D1 / 32, HDIM / 32), 256, 0, stream>>>(s1_W2, w2s1, HDIM, D1);
    transpose_cast<<<dim3(D1 / 32, HDIM / 32), 256, 0, stream>>>(t1_W2, w2t1, HDIM, D1);
    transpose_cast<<<dim3(D1 / 32, HDIM / 32), 256, 0, stream>>>(s2_W2, w2s2, HDIM, D1);
    transpose_cast<<<dim3(D1 / 32, HDIM / 32), 256, 0, stream>>>(t2_W2, w2t2, HDIM, D1);

    for (int c = 0; c < NC; ++c) {
      const long moff = (long)c * Mrows;
      unsigned short* xA = x2b + moff * D1;
      gemm8<<<dim3(16, Mrows / 256, 2), 512, 0, stream>>>(xA, xA, D1, w1s1, w1t1,
          s1_b1, t1_b1, h, h + 4096, 2 * HDIM, D1, 1);
      gemm8<<<dim3(4, Mrows / 256, 2), 512, 0, stream>>>(h, h + 4096, 2 * HDIM,
          w2s1, w2t1, s1_b2, t1_b2, xA, tb, D1, HDIM, 0);
      couple<<<Mrows, 256, 0, stream>>>(xA, tb, x, y_out, xA, ld_out, moff, 0, 0);
      gemm8<<<dim3(16, Mrows / 256, 2), 512, 0, stream>>>(xA, xA, D1, w1s2, w1t2,
          s2_b1, t2_b1, h, h + 4096, 2 * HDIM, D1, 1);
      gemm8<<<dim3(4, Mrows / 256, 2), 512, 0, stream>>>(h, h + 4096, 2 * HDIM,
          w2s2, w2t2, s2_b2, t2_b2, xA, tb, D1, HDIM, 0);
      couple<<<Mrows, 256, 0, stream>>>(xA, tb, x, y_out, nullptr, ld_out, moff, D1, 1);
    }
  }
}

// Round 3
// 763.706 us; speedup vs baseline: 1.1994x; 1.0918x over previous
//
#include <hip/hip_runtime.h>
#include <cstdint>
#include <cstddef>

// Problem dims
#define BDIM 8192
#define D1 1024
#define HDIM 4096

typedef __attribute__((ext_vector_type(8))) short short8;
typedef __attribute__((ext_vector_type(4))) float f32x4;
typedef __attribute__((ext_vector_type(4))) unsigned short u16x4;

__device__ inline void async_load16(const void* g, void* l) {
  __builtin_amdgcn_global_load_lds(
      (const __attribute__((address_space(1))) void*)g,
      (__attribute__((address_space(3))) void*)l,
      16 /*bytes*/, 0 /*offset*/, 0 /*aux*/);
}

__device__ inline unsigned short f2bf(float f) {
  union { float f; uint32_t u; } v; v.f = f;
  uint32_t u = v.u;
  uint32_t r = u + 0x7FFFu + ((u >> 16) & 1u);  // RNE
  return (unsigned short)(r >> 16);
}
__device__ inline float bf2f(unsigned short u) {
  union { uint32_t u; float f; } v; v.u = (uint32_t)u << 16; return v.f;
}

// ---------------------------------------------------------------------------
// 256x256 8-wave GEMM: C = act(A @ B^T + bias), bf16 in/out.
// A[M,K] row-major (stride lda), B[N,K] row-major (stride K), C[M,*] stride ldc.
// gridDim.z = 2 selects the (A,B,bias,C) tuple -> two GEMMs in one launch.
// Schedule: per K-tile (BK=64) 4 segments; each segment:
//   {ds_read frag subtile | stage 1 half-tile (2x global_load_lds)} ; [vmcnt(4)]
//   s_barrier ; setprio(1) ; 16x MFMA ; setprio(0)   <- NO trailing barrier:
// the next segment's ds_reads/stage issue while the MFMA pipe drains (the
// m201/m196 fine interleave). Hazards: stage always writes NB, reads always
// read BUF (disjoint); vmcnt(4)+barrier precedes first read of freshly staged
// slice (s2->s3 for slice1, s4->next-s1 for slice0); cross-tile WAR on slice0
// is 2+ barriers separated. vmcnt never drains to 0 in the main loop.
// LDS: [2buf][2slice][256 rows][32 cols] bf16 per matrix = 64KB+64KB = 128KB.
// Swizzle: 16B slot p holds logical k-group p ^ ((row>>1)&3) (involution),
// applied on the pre-swizzled global source (stage) and on ds_read -> 2-way.
// ---------------------------------------------------------------------------
__global__ __launch_bounds__(512, 2)
void gemm8(const unsigned short* __restrict__ A0,
           const unsigned short* __restrict__ A1, int lda,
           const unsigned short* __restrict__ B0,
           const unsigned short* __restrict__ B1,
           const float* __restrict__ bias0, const float* __restrict__ bias1,
           unsigned short* __restrict__ C0, unsigned short* __restrict__ C1,
           int ldc, int K, int relu) {
  __shared__ __align__(16) unsigned short smem[65536];  // A:[0,32768) B:[32768,65536)

  const int z = blockIdx.z;
  const unsigned short* A  = z ? A1 : A0;
  const unsigned short* Bw = z ? B1 : B0;
  const float* biasP       = z ? bias1 : bias0;
  unsigned short* C        = z ? C1 : C0;

  // bijective XCD swizzle (m204)
  const int nX  = gridDim.x;
  const int nwg = gridDim.x * gridDim.y;
  const int bid = blockIdx.y * gridDim.x + blockIdx.x;
  const int q = nwg >> 3, r = nwg & 7;
  const int xcd = bid & 7, rest = bid >> 3;
  const int wg = (xcd < r ? xcd * (q + 1) : r * (q + 1) + (xcd - r) * q) + rest;
  const int tm = wg / nX, tn = wg % nX;
  const int m0 = tm * 256, n0 = tn * 256;

  const int tid  = threadIdx.x;
  const int wave = tid >> 6, lane = tid & 63;
  const int quad = lane >> 4, l15 = lane & 15;
  const int wm = wave >> 2, wn = wave & 3;   // 2 x 4 wave grid; wave tile 128x64

  // staging source (pre-swizzled global address; LDS dest stays linear)
  const int sr    = tid >> 2;                         // 0..127
  const int sslot = (tid & 3) ^ ((tid >> 3) & 3);     // involutive 16B-slot swizzle
  const unsigned short* gA = A  + (long)(m0 + sr) * lda + sslot * 8;
  const unsigned short* gB = Bw + (long)(n0 + sr) * K   + sslot * 8;

  // LDS read bases (swizzled)
  const int swz = ((quad ^ ((l15 >> 1) & 3)) << 3);   // ushort units
  const unsigned short* aB = smem + wm * 4096  + l15 * 32 + swz;
  const unsigned short* bB = smem + 32768 + wn * 2048 + l15 * 32 + swz;

  f32x4 acc[8][4] = {};
  const int NT = K >> 6;

#define STAGE_A(NB, SL, KT) { \
  unsigned short* lw = smem + (NB)*16384 + (SL)*8192 + wave*512; \
  const unsigned short* g = gA + (long)(KT)*64 + (SL)*32; \
  async_load16(g, lw); \
  async_load16(g + 128*(long)lda, lw + 4096); }

#define STAGE_B(NB, SL, KT) { \
  unsigned short* lw = smem + 32768 + (NB)*16384 + (SL)*8192 + wave*512; \
  const unsigned short* g = gB + (long)(KT)*64 + (SL)*32; \
  async_load16(g, lw); \
  async_load16(g + 128*(long)K, lw + 4096); }

#define READ_A(dst, BUF, SL, MH) { \
  const unsigned short* p = aB + (BUF)*16384 + (SL)*8192 + (MH)*2048; \
  dst[0] = *(const short8*)(p);        dst[1] = *(const short8*)(p + 512); \
  dst[2] = *(const short8*)(p + 1024); dst[3] = *(const short8*)(p + 1536); }

#define READ_B(dst, BUF, SL) { \
  const unsigned short* p = bB + (BUF)*16384 + (SL)*8192; \
  dst[0] = *(const short8*)(p);        dst[1] = *(const short8*)(p + 512); \
  dst[2] = *(const short8*)(p + 1024); dst[3] = *(const short8*)(p + 1536); }

#define MFMA16(MH, AV, BV) \
  _Pragma("unroll") \
  for (int mt = 0; mt < 4; ++mt) { \
    _Pragma("unroll") \
    for (int nt = 0; nt < 4; ++nt) { \
      acc[(MH)*4 + mt][nt] = __builtin_amdgcn_mfma_f32_16x16x32_bf16( \
          AV[mt], BV[nt], acc[(MH)*4 + mt][nt], 0, 0, 0); \
    } }

#define BARRIER() asm volatile("s_barrier" ::: "memory")
#define VMCNT4()  asm volatile("s_waitcnt vmcnt(4)" ::: "memory")

#define TILE_BODY(BUF, NB, TNX) { \
  short8 a0[4], a1[4], b0v[4], b1v[4]; \
  /* s1: (mLo, k0) */ \
  READ_A(a0, BUF, 0, 0); READ_B(b0v, BUF, 0); \
  STAGE_A(NB, 0, TNX); \
  BARRIER(); \
  __builtin_amdgcn_s_setprio(1); MFMA16(0, a0, b0v); __builtin_amdgcn_s_setprio(0); \
  /* s2: (mHi, k0) */ \
  READ_A(a1, BUF, 0, 1); \
  STAGE_B(NB, 0, TNX); \
  VMCNT4(); \
  BARRIER(); \
  __builtin_amdgcn_s_setprio(1); MFMA16(1, a1, b0v); __builtin_amdgcn_s_setprio(0); \
  /* s3: (mLo, k1) */ \
  READ_A(a0, BUF, 1, 0); READ_B(b1v, BUF, 1); \
  STAGE_A(NB, 1, TNX); \
  BARRIER(); \
  __builtin_amdgcn_s_setprio(1); MFMA16(0, a0, b1v); __builtin_amdgcn_s_setprio(0); \
  /* s4: (mHi, k1) */ \
  READ_A(a1, BUF, 1, 1); \
  STAGE_B(NB, 1, TNX); \
  VMCNT4(); \
  BARRIER(); \
  __builtin_amdgcn_s_setprio(1); MFMA16(1, a1, b1v); __builtin_amdgcn_s_setprio(0); \
}

  // prologue: stage tile 0 into buf 0 (order: A-k0, B-k0, A-k1, B-k1)
  STAGE_A(0, 0, 0); STAGE_B(0, 0, 0); STAGE_A(0, 1, 0); STAGE_B(0, 1, 0);
  VMCNT4();        // k0 slices landed; k1 (4 loads) stays in flight
  BARRIER();

#pragma unroll 1
  for (int t = 0; t < NT; t += 2) {
    const int tnx1 = t + 1;                       // always < NT (NT even)
    const int tnx2 = (t + 2 < NT) ? t + 2 : NT - 1;  // clamp: harmless re-stage
    TILE_BODY(0, 1, tnx1);
    TILE_BODY(1, 0, tnx2);
  }

  // ---- epilogue: drain stage loads, then LDS-bounce for coalesced C writes --
  asm volatile("s_waitcnt vmcnt(0)" ::: "memory");
  BARRIER();   // all waves past MFMA (lgkm-complete) and all loads landed

  unsigned short* sc = smem + wave * 8192;  // private 128x64 bf16 scratch/wave
#pragma unroll
  for (int nt = 0; nt < 4; ++nt) {
    const int col = n0 + wn * 64 + nt * 16 + l15;
    const float bv = biasP[col];
#pragma unroll
    for (int mt = 0; mt < 8; ++mt) {
#pragma unroll
      for (int rr = 0; rr < 4; ++rr) {
        const int lrow = mt * 16 + quad * 4 + rr;
        float v = acc[mt][nt][rr] + bv;
        if (relu) v = v > 0.f ? v : 0.f;
        // bank-conflict-free scratch: XOR col bits 4-5 with row's quad
        sc[lrow * 64 + ((nt * 16 + l15) ^ (((lrow >> 2) & 3) << 4))] = f2bf(v);
      }
    }
  }
  // per-wave private region: no barrier needed (wave-ordered DS ops)
  const long rowbase = m0 + wm * 128;
  const int colbase  = n0 + wn * 64;
#pragma unroll
  for (int i = 0; i < 16; ++i) {
    const int L   = i * 1024 + lane * 16;   // byte offset in wave scratch
    const int row = L >> 7;
    const int sp  = (L & 127) >> 4;
    const int cg  = sp ^ ((((row) >> 2) & 3) << 1);   // undo col-bit-4/5 XOR (slot bits 1-2)
    short8 v = *(const short8*)&sc[row * 64 + sp * 8];
    *(short8*)&C[(rowbase + row) * (long)ldc + colbase + cg * 8] = v;
  }

#undef STAGE_A
#undef STAGE_B
#undef READ_A
#undef READ_B
#undef MFMA16
#undef BARRIER
#undef VMCNT4
#undef TILE_BODY
}

// ---------------------------------------------------------------------------
// Coupling epilogue: sv=tanh(s); y = x[:,xoff+c]*exp(sv)+t; optional y->bf16;
// ld[row] = (or +=) rowsum(sv). One block per row, no atomics.
// NOTE: sb and y1b may alias (in-place); no __restrict__ on them.
// ---------------------------------------------------------------------------
__global__ __launch_bounds__(256)
void couple(const unsigned short* sb, const unsigned short* __restrict__ tb,
            const float* __restrict__ x, float* __restrict__ y,
            unsigned short* y1b, float* __restrict__ ld,
            long growoff, int xoff, int addld) {
  __shared__ float wsum[4];
  const int row = blockIdx.x;
  const long grow = growoff + row;
  const int c = threadIdx.x * 4;

  u16x4 sv4 = *(const u16x4*)&sb[(long)row * 1024 + c];
  u16x4 tv4 = *(const u16x4*)&tb[(long)row * 1024 + c];
  f32x4 xv  = *(const f32x4*)&x[grow * 2048 + xoff + c];
  f32x4 yv;
  unsigned short yb[4];
  float rs = 0.f;
#pragma unroll
  for (int j = 0; j < 4; ++j) {
    float s  = bf2f(sv4[j]);
    float t  = bf2f(tv4[j]);
    float sv = tanhf(s);           // SCALE_LIMIT = 1.0
    rs += sv;
    float yy = xv[j] * __expf(sv) + t;
    yv[j] = yy;
    yb[j] = f2bf(yy);
  }
  *(f32x4*)&y[grow * 2048 + xoff + c] = yv;
  if (y1b) {
    u16x4 o; o[0] = yb[0]; o[1] = yb[1]; o[2] = yb[2]; o[3] = yb[3];
    *(u16x4*)&y1b[(long)row * 1024 + c] = o;
  }
#pragma unroll
  for (int o = 32; o > 0; o >>= 1) rs += __shfl_down(rs, o);
  const int wv = threadIdx.x >> 6, ln = threadIdx.x & 63;
  if (ln == 0) wsum[wv] = rs;
  __syncthreads();
  if (threadIdx.x == 0) {
    float tot = wsum[0] + wsum[1] + wsum[2] + wsum[3];
    if (addld) ld[grow] += tot; else ld[grow] = tot;
  }
}

// ---------------------------------------------------------------------------
// Transpose + fp32->bf16 cast: in[R,C] fp32 -> out[C,R] bf16.
// ---------------------------------------------------------------------------
__global__ __launch_bounds__(256)
void transpose_cast(const float* __restrict__ in, unsigned short* __restrict__ out,
                    int R, int C) {
  __shared__ float tile[32][33];
  const int bx = blockIdx.x * 32;
  const int by = blockIdx.y * 32;
  const int tx = threadIdx.x & 31;
  const int ty = threadIdx.x >> 5;
  for (int j = ty; j < 32; j += 8)
    tile[j][tx] = in[(long)(by + j) * C + bx + tx];
  __syncthreads();
  for (int j = ty; j < 32; j += 8)
    out[(long)(bx + j) * R + by + tx] = f2bf(tile[tx][j]);
}

// x (B, 2048) fp32 -> x2 bf16 packed (B, 1024)
__global__ __launch_bounds__(256)
void cast_x2(const float* __restrict__ x, unsigned short* __restrict__ x2b) {
  long i = (long)blockIdx.x * 256 + threadIdx.x;
  long row = i >> 10, col = i & 1023;
  x2b[i] = f2bf(x[row * (2 * D1) + D1 + col]);
}

// ---------------------------------------------------------------------------
extern "C" void kernel_launch(void* const* d_in, const int* in_sizes, int n_in,
                              void* d_out, int out_size, void* d_ws, size_t ws_size,
                              hipStream_t stream) {
  const float* x     = (const float*)d_in[0];
  const float* s1_W1 = (const float*)d_in[1];
  const float* s1_b1 = (const float*)d_in[2];
  const float* s1_W2 = (const float*)d_in[3];
  const float* s1_b2 = (const float*)d_in[4];
  const float* t1_W1 = (const float*)d_in[5];
  const float* t1_b1 = (const float*)d_in[6];
  const float* t1_W2 = (const float*)d_in[7];
  const float* t1_b2 = (const float*)d_in[8];
  const float* s2_W1 = (const float*)d_in[9];
  const float* s2_b1 = (const float*)d_in[10];
  const float* s2_W2 = (const float*)d_in[11];
  const float* s2_b2 = (const float*)d_in[12];
  const float* t2_W1 = (const float*)d_in[13];
  const float* t2_b1 = (const float*)d_in[14];
  const float* t2_W2 = (const float*)d_in[15];
  const float* t2_b2 = (const float*)d_in[16];

  const size_t MB = 1024UL * 1024UL;
  float* y_out  = (float*)d_out;                           // (B, 2048)
  float* ld_out = (float*)d_out + (long)BDIM * (2 * D1);   // (B,)
  char* ws = (char*)d_ws;

  if (ws_size >= 192 * MB) {
    // NC=1 layout (192MB): w1a@0 w1b@8 w2a@16 w2b@24 | x2b/sbuf@32 (16MB)
    //                      tbuf@48 (16MB) | h@64 (128MB)
    unsigned short* w1a = (unsigned short*)(ws + 0 * MB);
    unsigned short* w1b = (unsigned short*)(ws + 8 * MB);
    unsigned short* w2a = (unsigned short*)(ws + 16 * MB);
    unsigned short* w2b = (unsigned short*)(ws + 24 * MB);
    unsigned short* x2b = (unsigned short*)(ws + 32 * MB);  // x2 -> sbuf -> y1b -> sbuf
    unsigned short* tb  = (unsigned short*)(ws + 48 * MB);
    unsigned short* h   = (unsigned short*)(ws + 64 * MB);

    cast_x2<<<(BDIM * D1) / 256, 256, 0, stream>>>(x, x2b);
    transpose_cast<<<dim3(HDIM / 32, D1 / 32), 256, 0, stream>>>(s1_W1, w1a, D1, HDIM);
    transpose_cast<<<dim3(HDIM / 32, D1 / 32), 256, 0, stream>>>(t1_W1, w1b, D1, HDIM);
    transpose_cast<<<dim3(D1 / 32, HDIM / 32), 256, 0, stream>>>(s1_W2, w2a, HDIM, D1);
    transpose_cast<<<dim3(D1 / 32, HDIM / 32), 256, 0, stream>>>(t1_W2, w2b, HDIM, D1);

    // ---- stage 1 ----
    gemm8<<<dim3(16, 32, 2), 512, 0, stream>>>(x2b, x2b, D1, w1a, w1b,
        s1_b1, t1_b1, h, h + 4096, 2 * HDIM, D1, 1);
    // stage-1 W1 dead -> re-transpose stage-2 W1 into same buffers
    transpose_cast<<<dim3(HDIM / 32, D1 / 32), 256, 0, stream>>>(s2_W1, w1a, D1, HDIM);
    transpose_cast<<<dim3(HDIM / 32, D1 / 32), 256, 0, stream>>>(t2_W1, w1b, D1, HDIM);
    gemm8<<<dim3(4, 32, 2), 512, 0, stream>>>(h, h + 4096, 2 * HDIM, w2a, w2b,
        s1_b2, t1_b2, x2b /*sbuf*/, tb, D1, HDIM, 0);
    transpose_cast<<<dim3(D1 / 32, HDIM / 32), 256, 0, stream>>>(s2_W2, w2a, HDIM, D1);
    transpose_cast<<<dim3(D1 / 32, HDIM / 32), 256, 0, stream>>>(t2_W2, w2b, HDIM, D1);
    couple<<<BDIM, 256, 0, stream>>>(x2b, tb, x, y_out, x2b /*y1b in place*/,
                                     ld_out, 0, 0, 0);
    // ---- stage 2 ----
    gemm8<<<dim3(16, 32, 2), 512, 0, stream>>>(x2b, x2b, D1, w1a, w1b,
        s2_b1, t2_b1, h, h + 4096, 2 * HDIM, D1, 1);
    gemm8<<<dim3(4, 32, 2), 512, 0, stream>>>(h, h + 4096, 2 * HDIM, w2a, w2b,
        s2_b2, t2_b2, x2b /*sbuf*/, tb, D1, HDIM, 0);
    couple<<<BDIM, 256, 0, stream>>>(x2b, tb, x, y_out, nullptr, ld_out, 0, D1, 1);
  } else {
    // Chunked fallback: all 8 weight buffers persistent (64MB) + x2b (16MB)
    // + per-chunk tbuf (16/NC) + h (128/NC).
    int NC = 2;
    while (NC < 16) {
      size_t need = 80 * MB + (16 * MB) / NC + (128 * MB) / NC;
      if (need <= ws_size) break;
      NC <<= 1;
    }
    const int Mrows = BDIM / NC;
    unsigned short* w1s1 = (unsigned short*)(ws + 0 * MB);
    unsigned short* w1t1 = (unsigned short*)(ws + 8 * MB);
    unsigned short* w1s2 = (unsigned short*)(ws + 16 * MB);
    unsigned short* w1t2 = (unsigned short*)(ws + 24 * MB);
    unsigned short* w2s1 = (unsigned short*)(ws + 32 * MB);
    unsigned short* w2t1 = (unsigned short*)(ws + 40 * MB);
    unsigned short* w2s2 = (unsigned short*)(ws + 48 * MB);
    unsigned short* w2t2 = (unsigned short*)(ws + 56 * MB);
    unsigned short* x2b  = (unsigned short*)(ws + 64 * MB);
    unsigned short* tb   = (unsigned short*)(ws + 80 * MB);
    unsigned short* h    = (unsigned short*)(ws + 80 * MB + (16 * MB) / NC);

    cast_x2<<<(BDIM * D1) / 256, 256, 0, stream>>>(x, x2b);
    transpose_cast<<<dim3(HDIM / 32, D1 / 32), 256, 0, stream>>>(s1_W1, w1s1, D1, HDIM);
    transpose_cast<<<dim3(HDIM / 32, D1 / 32), 256, 0, stream>>>(t1_W1, w1t1, D1, HDIM);
    transpose_cast<<<dim3(HDIM / 32, D1 / 32), 256, 0, stream>>>(s2_W1, w1s2, D1, HDIM);
    transpose_cast<<<dim3(HDIM / 32, D1 / 32), 256, 0, stream>>>(t2_W1, w1t2, D1, HDIM);
    transpose_cast<<<dim3(D1 / 32, HDIM / 32), 256, 0, stream>>>(s1_W2, w2s1, HDIM, D1);
    transpose_cast<<<dim3(D1 / 32, HDIM / 32), 256, 0, stream>>>(t1_W2, w2t1, HDIM, D1);
    transpose_cast<<<dim3(D1 / 32, HDIM / 32), 256, 0, stream>>>(s2_W2, w2s2, HDIM, D1);
    transpose_cast<<<dim3(D1 / 32, HDIM / 32), 256, 0, stream>>>(t2_W2, w2t2, HDIM, D1);

    for (int c = 0; c < NC; ++c) {
      const long moff = (long)c * Mrows;
      unsigned short* xA = x2b + moff * D1;
      gemm8<<<dim3(16, Mrows / 256, 2), 512, 0, stream>>>(xA, xA, D1, w1s1, w1t1,
          s1_b1, t1_b1, h, h + 4096, 2 * HDIM, D1, 1);
      gemm8<<<dim3(4, Mrows / 256, 2), 512, 0, stream>>>(h, h + 4096, 2 * HDIM,
          w2s1, w2t1, s1_b2, t1_b2, xA, tb, D1, HDIM, 0);
      couple<<<Mrows, 256, 0, stream>>>(xA, tb, x, y_out, xA, ld_out, moff, 0, 0);
      gemm8<<<dim3(16, Mrows / 256, 2), 512, 0, stream>>>(xA, xA, D1, w1s2, w1t2,
          s2_b1, t2_b1, h, h + 4096, 2 * HDIM, D1, 1);
      gemm8<<<dim3(4, Mrows / 256, 2), 512, 0, stream>>>(h, h + 4096, 2 * HDIM,
          w2s2, w2t2, s2_b2, t2_b2, xA, tb, D1, HDIM, 0);
      couple<<<Mrows, 256, 0, stream>>>(xA, tb, x, y_out, nullptr, ld_out, moff, D1, 1);
    }
  }
}